// Round 13
// baseline (306.601 us; speedup 1.0000x reference)
//
#include <hip/hip_runtime.h>

// QuantizedLinear on MI355X — round 13: r12 frame, 32x32x16 MFMA (half the
// matrix instructions).
//   out = (x @ H) @ dequant(W)^T + bias
// Both GEMMs single-term bf16 (validated r8-r12): GEMM1 xh·Hh, GEMM2 xrh·Wb,
// Wb = bf16((nibble-8)*scale).
// r12 accounting: tile = 2212 cyc ≈ MFMA-busy 1150 + LDS-read 1130 —
// serialized; r11 interleave null; r12 depth null. Hypothesis: per-MFMA
// issue/dependency overhead (~18 cyc effective vs 4.85 ideal at 2 waves/SIMD)
// dominates. Test: same FLOP / same LDS bytes / same 12 ds_read_b128 per
// wave-tile, but 16x v_mfma_f32_32x32x16_bf16 instead of 32x 16x16x32.
// C/D layout (m74/m101 verified): col=lane&31, row=(reg&3)+8*(reg>>2)
// +4*(lane>>5). A/B operand: row=lane&31, k-chunk=(lane>>5)*8 (2xK analog of
// the proven 16x16 mapping). All else identical to r12: 256x256 tile, BK=32,
// 8 waves (2Mx4N), 4-slot ring, depth-3 prefetch, counted vmcnt(8), 64 B-row
// XOR swizzle both-sides, XCD swizzle. Requires 128 MiB d_ws (192 proven).

#define N_TOK 4096
#define K_DIM 4096
#define M_DIM 4096
#define NT    128          // K tiles (4096/32)

typedef __attribute__((ext_vector_type(8))) short s8v;       // 8 bf16 (4 VGPR)
typedef __attribute__((ext_vector_type(16))) float f32x16;
typedef __attribute__((ext_vector_type(4))) unsigned short u16x4;
typedef __attribute__((ext_vector_type(8))) unsigned short u16x8;

#define AS1(p) ((const __attribute__((address_space(1))) void*)(p))
#define AS3(p) ((__attribute__((address_space(3))) void*)(p))

__device__ __forceinline__ unsigned short bf16_rne(float f) {
    unsigned int u = __float_as_uint(f);
    unsigned int r = (u + 0x7FFFu + ((u >> 16) & 1u)) >> 16;
    return (unsigned short)r;
}

// ---------- prep: cast fp32 -> bf16 (RNE), x8 vectorized ----------
__global__ __launch_bounds__(256) void prep_cast(const float* __restrict__ in,
                                                 unsigned short* __restrict__ ph) {
    size_t i = ((size_t)blockIdx.x * 256 + threadIdx.x) * 8;
    float4 v0 = *reinterpret_cast<const float4*>(&in[i]);
    float4 v1 = *reinterpret_cast<const float4*>(&in[i + 4]);
    u16x8 h;
    h[0] = bf16_rne(v0.x); h[1] = bf16_rne(v0.y);
    h[2] = bf16_rne(v0.z); h[3] = bf16_rne(v0.w);
    h[4] = bf16_rne(v1.x); h[5] = bf16_rne(v1.y);
    h[6] = bf16_rne(v1.z); h[7] = bf16_rne(v1.w);
    *reinterpret_cast<u16x8*>(&ph[i]) = h;
}

// ---------- prep: transpose H -> Th (bf16) stored [n][k] ----------
__global__ __launch_bounds__(256) void prep_hT(const float* __restrict__ H,
                                               unsigned short* __restrict__ Th) {
    __shared__ float tile[64][65];
    const int t = threadIdx.x;
    const int tx = t & 15, ty = t >> 4;
    const int c0 = blockIdx.x * 64, r0 = blockIdx.y * 64;
    #pragma unroll
    for (int rr = 0; rr < 4; ++rr) {
        int r = ty + rr * 16;
        float4 v = *reinterpret_cast<const float4*>(&H[(size_t)(r0 + r) * K_DIM + c0 + tx * 4]);
        tile[r][tx * 4 + 0] = v.x;
        tile[r][tx * 4 + 1] = v.y;
        tile[r][tx * 4 + 2] = v.z;
        tile[r][tx * 4 + 3] = v.w;
    }
    __syncthreads();
    #pragma unroll
    for (int rr = 0; rr < 4; ++rr) {
        int c = ty + rr * 16;
        u16x4 h;
        #pragma unroll
        for (int e = 0; e < 4; ++e) h[e] = bf16_rne(tile[tx * 4 + e][c]);
        size_t o = (size_t)(c0 + c) * K_DIM + r0 + tx * 4;
        *reinterpret_cast<u16x4*>(&Th[o]) = h;
    }
}

// ---------- prep: dequant int4 -> bf16 (nibble-8)*scale ----------
__global__ __launch_bounds__(256) void prep_w(const int* __restrict__ wd,
                                              const float* __restrict__ ws,
                                              unsigned short* __restrict__ Wb) {
    const int o = blockIdx.x, t = threadIdx.x;
    const int4* p = reinterpret_cast<const int4*>(&wd[(size_t)o * (K_DIM / 2) + t * 8]);
    int4 w0 = p[0], w1 = p[1];
    const float s = ws[o * 32 + (t >> 3)];   // k0 = t*16, group = t*16/128
    int wv[8] = {w0.x, w0.y, w0.z, w0.w, w1.x, w1.y, w1.z, w1.w};
    u16x8 h0, h1;
    #pragma unroll
    for (int m = 0; m < 8; ++m) {
        unsigned short lo = bf16_rne((float)((wv[m] & 0xF) - 8) * s);
        unsigned short hi = bf16_rne((float)(((wv[m] >> 4) & 0xF) - 8) * s);
        if (m < 4) { h0[2 * m] = lo; h0[2 * m + 1] = hi; }
        else       { h1[2 * (m - 4)] = lo; h1[2 * (m - 4) + 1] = hi; }
    }
    size_t oo = (size_t)o * K_DIM + t * 16;
    *reinterpret_cast<u16x8*>(&Wb[oo]) = h0;
    *reinterpret_cast<u16x8*>(&Wb[oo + 8]) = h1;
}

// ---------- 256x256 GEMM, BK=32, 4-slot ring, depth-3, 32x32x16 MFMA ----------
// A [m][k] bf16, B [n][k] bf16. 8 waves 2x4; wave owns 128x64 =
// 4(M) x 2(N) fragments of 32x32. MODE 0: C -> bf16. MODE 1: C -> f32+bias.
template <int MODE>
__global__ __launch_bounds__(512) void gemm_cv(const unsigned short* __restrict__ A,
                                               const unsigned short* __restrict__ B,
                                               const float* __restrict__ bias,
                                               unsigned short* __restrict__ Cb,
                                               float* __restrict__ Cf) {
    extern __shared__ unsigned short sm[];   // 4 slots x (A 8192 | B 8192) ushorts
    const int t = threadIdx.x;
    const int lane = t & 63;
    const int wid = __builtin_amdgcn_readfirstlane(t >> 6);
    const int wr = wid >> 2, wc = wid & 3;   // 2 x 4 wave grid

    // XCD-aware bijective swizzle: 256 blocks, 8 XCDs, 256%8==0
    const int fid = blockIdx.x;
    const int sw = (fid & 7) * 32 + (fid >> 3);
    const int bm = (sw >> 4) * 256;
    const int bn = (sw & 15) * 256;

    // staging: per matrix tile 1024 chunks (256 rows x 4 chunks of 16B),
    // 2 chunks/thread. LDS dest linear; SOURCE pre-swizzled:
    // logical chunk = physical ^ ((row>>1)&3)  (r4/r6/r10 proven-zero layout).
    size_t ga[2], gb[2];
    int lb[2];
    #pragma unroll
    for (int j = 0; j < 2; ++j) {
        int ch = wid * 128 + j * 64 + lane;
        int row = ch >> 2, qp = ch & 3;
        int qs = qp ^ ((row >> 1) & 3);
        ga[j] = (size_t)(bm + row) * K_DIM + qs * 8;
        gb[j] = (size_t)(bn + row) * K_DIM + qs * 8;
        lb[j] = (wid * 128 + j * 64) * 8;    // wave-uniform, HW adds lane*16B
    }

    // fragment reads (32x32x16): row = lane&31, k-chunk = s*2 + (lane>>5),
    // physical chunk = logical ^ ((row>>1)&3); ushort offset row*32 + chunk*8
    const int l31 = lane & 31, l5 = lane >> 5;
    int aoff[4][2], boff[2][2], colj[2];
    #pragma unroll
    for (int i = 0; i < 4; ++i) {
        int ra = wr * 128 + i * 32 + l31;
        #pragma unroll
        for (int s = 0; s < 2; ++s)
            aoff[i][s] = ra * 32 + (((s << 1) | l5) ^ ((ra >> 1) & 3)) * 8;
    }
    #pragma unroll
    for (int j = 0; j < 2; ++j) {
        int rb = wc * 64 + j * 32 + l31;
        #pragma unroll
        for (int s = 0; s < 2; ++s)
            boff[j][s] = rb * 32 + (((s << 1) | l5) ^ ((rb >> 1) & 3)) * 8;
        colj[j] = bn + wc * 64 + j * 32 + l31;
    }

    f32x16 acc[4][2];
    #pragma unroll
    for (int i = 0; i < 4; ++i)
        #pragma unroll
        for (int j = 0; j < 2; ++j) acc[i][j] = (f32x16)(0.0f);

#define STAGE(tt)                                                                                      \
    {                                                                                                  \
        const int _sl = ((tt) & 3) * 16384;                                                            \
        _Pragma("unroll")                                                                              \
        for (int j = 0; j < 2; ++j) {                                                                  \
            __builtin_amdgcn_global_load_lds(AS1(A + ga[j] + (tt) * 32), AS3(&sm[_sl + lb[j]]), 16, 0, 0); \
            __builtin_amdgcn_global_load_lds(AS1(B + gb[j] + (tt) * 32), AS3(&sm[_sl + 8192 + lb[j]]), 16, 0, 0); \
        }                                                                                              \
    }

#define COMPUTE(tt)                                                                                    \
    {                                                                                                  \
        const unsigned short* _pa = &sm[((tt) & 3) * 16384];                                           \
        const unsigned short* _pb = _pa + 8192;                                                        \
        _Pragma("unroll")                                                                              \
        for (int s = 0; s < 2; ++s) {                                                                  \
            s8v av[4], bv[2];                                                                          \
            _Pragma("unroll")                                                                          \
            for (int i = 0; i < 4; ++i) av[i] = *reinterpret_cast<const s8v*>(&_pa[aoff[i][s]]);       \
            _Pragma("unroll")                                                                          \
            for (int j = 0; j < 2; ++j) bv[j] = *reinterpret_cast<const s8v*>(&_pb[boff[j][s]]);       \
            _Pragma("unroll")                                                                          \
            for (int i = 0; i < 4; ++i)                                                                \
                _Pragma("unroll")                                                                      \
                for (int j = 0; j < 2; ++j)                                                            \
                    acc[i][j] = __builtin_amdgcn_mfma_f32_32x32x16_bf16(av[i], bv[j], acc[i][j], 0, 0, 0); \
        }                                                                                              \
    }

#define SYNCN(N)                                                                                       \
    asm volatile("s_waitcnt vmcnt(" #N ")" ::: "memory");                                              \
    __builtin_amdgcn_s_barrier();                                                                      \
    __builtin_amdgcn_sched_barrier(0);

    // prologue: stage tiles 0,1,2 (12 loads/thread); retire tile 0
    // (vmcnt(8) leaves tiles 1,2 = 8 loads in flight)
    STAGE(0);
    STAGE(1);
    STAGE(2);
    SYNCN(8);
    // steady state: issue t+3 (slot freed by iter t-1), compute t,
    // retire t+1's 4 oldest keeping t+2,t+3's 8 in flight.
    for (int t = 0; t + 3 < NT; ++t) {
        STAGE(t + 3);
        COMPUTE(t);
        SYNCN(8);
    }
    // tail: tiles NT-2, NT-1 in flight (8 loads)
    COMPUTE(NT - 3);
    SYNCN(4);          // retire tile NT-2's loads
    COMPUTE(NT - 2);
    SYNCN(0);          // retire tile NT-1's loads
    COMPUTE(NT - 1);
#undef STAGE
#undef COMPUTE
#undef SYNCN

    // epilogue — 32x32 C/D layout [m74/m101]: col = lane&31,
    // row = (reg&3) + 8*(reg>>2) + 4*(lane>>5), reg in [0,16)
    if (MODE == 0) {
        #pragma unroll
        for (int i = 0; i < 4; ++i)
            #pragma unroll
            for (int j = 0; j < 2; ++j)
                #pragma unroll
                for (int r = 0; r < 16; ++r) {
                    int row = bm + wr * 128 + i * 32 + (r & 3) + 8 * (r >> 2) + 4 * l5;
                    Cb[(size_t)row * K_DIM + colj[j]] = bf16_rne(acc[i][j][r]);
                }
    } else {
        float bj[2];
        #pragma unroll
        for (int j = 0; j < 2; ++j) bj[j] = bias[colj[j]];
        #pragma unroll
        for (int i = 0; i < 4; ++i)
            #pragma unroll
            for (int j = 0; j < 2; ++j)
                #pragma unroll
                for (int r = 0; r < 16; ++r) {
                    int row = bm + wr * 128 + i * 32 + (r & 3) + 8 * (r >> 2) + 4 * l5;
                    Cf[(size_t)row * M_DIM + colj[j]] = acc[i][j][r] + bj[j];
                }
    }
}

extern "C" void kernel_launch(void* const* d_in, const int* in_sizes, int n_in,
                              void* d_out, int out_size, void* d_ws, size_t ws_size,
                              hipStream_t stream) {
    const float* x      = (const float*)d_in[0];
    const float* had    = (const float*)d_in[1];
    const float* wscale = (const float*)d_in[2];
    const float* bias   = (const float*)d_in[3];
    const int*   wdata  = (const int*)d_in[4];
    float* out = (float*)d_out;

    const size_t SEG = (size_t)N_TOK * K_DIM * 2;   // 32 MiB
    char* w = (char*)d_ws;
    unsigned short* xh  = (unsigned short*)(w);            // [0,32Mi)
    unsigned short* Hh  = (unsigned short*)(w + SEG);      // [32,64Mi)
    unsigned short* xrh = (unsigned short*)(w + 2 * SEG);  // [64,96Mi)
    unsigned short* Wb  = (unsigned short*)(w + 3 * SEG);  // [96,128Mi)

    // allow 128 KiB dynamic LDS (host-side idempotent config; guarded so the
    // graph-captured replay path never re-executes it — proven r10-r12)
    static bool attr_done = false;
    if (!attr_done) {
        hipFuncSetAttribute((const void*)gemm_cv<0>,
                            hipFuncAttributeMaxDynamicSharedMemorySize, 131072);
        hipFuncSetAttribute((const void*)gemm_cv<1>,
                            hipFuncAttributeMaxDynamicSharedMemorySize, 131072);
        attr_done = true;
    }

    prep_cast<<<(N_TOK * K_DIM) / (256 * 8), 256, 0, stream>>>(x, xh);
    prep_hT<<<dim3(64, 64), 256, 0, stream>>>(had, Hh);
    prep_w<<<M_DIM, 256, 0, stream>>>(wdata, wscale, Wb);
    gemm_cv<0><<<256, 512, 131072, stream>>>(xh, Hh, nullptr, xrh, nullptr);
    gemm_cv<1><<<256, 512, 131072, stream>>>(xrh, Wb, bias, nullptr, out);
}

// Round 14
// 281.626 us; speedup vs baseline: 1.0887x; 1.0887x over previous
//
#include <hip/hip_runtime.h>

// QuantizedLinear on MI355X — round 14: r12 frame + register fragment pipeline.
//   out = (x @ H) @ dequant(W)^T + bias
// GEMM1 xh·Hh, GEMM2 xrh·Wb (Wb = bf16((nibble-8)*scale)) — validated r8-r12.
// r13 reverted (32x32 path had a 4-way-conflict read pattern; 16x16x32 is the
// proven-zero layout). Cycle model (r13 rederivation): per CU per K-tile,
// MFMA pipe = 64 instr x 19.4 cyc/SIMD = 1242 cyc, LDS-read = 96 KiB @ 85
// B/cyc = 1156 cyc; observed 2212 = serialized, because each wave's first
// MFMA waits for its LAST-batched ds_reads while all 8 waves burst reads
// post-barrier. Fix at register level:
//   (a) bv(u+1) read into regs DURING tile u's MFMAs (ring visibility: with
//       vmcnt(4), tile u+1 is retired+barrier'd by start of iter u);
//   (b) av JIT ping-pong: av[i+1] read between MFMA groups, spreading the
//       wave's 8 A-reads across its MFMA stream -> LDS pipe runs under the
//       matrix pipe instead of before it.
// SYNCN 8->4 (visibility one tile earlier; r12 proved depth is not the
// limiter). Same 256x256/BK=32/8-wave/4-slot ring/XOR-swizzle/XCD-swizzle.
// Requires 128 MiB d_ws (192 proven).

#define N_TOK 4096
#define K_DIM 4096
#define M_DIM 4096
#define NT    128          // K tiles (4096/32)

typedef __attribute__((ext_vector_type(8))) short s8v;       // 8 bf16 (4 VGPR)
typedef __attribute__((ext_vector_type(4))) float f32x4;
typedef __attribute__((ext_vector_type(4))) unsigned short u16x4;
typedef __attribute__((ext_vector_type(8))) unsigned short u16x8;

#define AS1(p) ((const __attribute__((address_space(1))) void*)(p))
#define AS3(p) ((__attribute__((address_space(3))) void*)(p))

__device__ __forceinline__ unsigned short bf16_rne(float f) {
    unsigned int u = __float_as_uint(f);
    unsigned int r = (u + 0x7FFFu + ((u >> 16) & 1u)) >> 16;
    return (unsigned short)r;
}

// ---------- prep: cast fp32 -> bf16 (RNE), x8 vectorized ----------
__global__ __launch_bounds__(256) void prep_cast(const float* __restrict__ in,
                                                 unsigned short* __restrict__ ph) {
    size_t i = ((size_t)blockIdx.x * 256 + threadIdx.x) * 8;
    float4 v0 = *reinterpret_cast<const float4*>(&in[i]);
    float4 v1 = *reinterpret_cast<const float4*>(&in[i + 4]);
    u16x8 h;
    h[0] = bf16_rne(v0.x); h[1] = bf16_rne(v0.y);
    h[2] = bf16_rne(v0.z); h[3] = bf16_rne(v0.w);
    h[4] = bf16_rne(v1.x); h[5] = bf16_rne(v1.y);
    h[6] = bf16_rne(v1.z); h[7] = bf16_rne(v1.w);
    *reinterpret_cast<u16x8*>(&ph[i]) = h;
}

// ---------- prep: transpose H -> Th (bf16) stored [n][k] ----------
__global__ __launch_bounds__(256) void prep_hT(const float* __restrict__ H,
                                               unsigned short* __restrict__ Th) {
    __shared__ float tile[64][65];
    const int t = threadIdx.x;
    const int tx = t & 15, ty = t >> 4;
    const int c0 = blockIdx.x * 64, r0 = blockIdx.y * 64;
    #pragma unroll
    for (int rr = 0; rr < 4; ++rr) {
        int r = ty + rr * 16;
        float4 v = *reinterpret_cast<const float4*>(&H[(size_t)(r0 + r) * K_DIM + c0 + tx * 4]);
        tile[r][tx * 4 + 0] = v.x;
        tile[r][tx * 4 + 1] = v.y;
        tile[r][tx * 4 + 2] = v.z;
        tile[r][tx * 4 + 3] = v.w;
    }
    __syncthreads();
    #pragma unroll
    for (int rr = 0; rr < 4; ++rr) {
        int c = ty + rr * 16;
        u16x4 h;
        #pragma unroll
        for (int e = 0; e < 4; ++e) h[e] = bf16_rne(tile[tx * 4 + e][c]);
        size_t o = (size_t)(c0 + c) * K_DIM + r0 + tx * 4;
        *reinterpret_cast<u16x4*>(&Th[o]) = h;
    }
}

// ---------- prep: dequant int4 -> bf16 (nibble-8)*scale ----------
__global__ __launch_bounds__(256) void prep_w(const int* __restrict__ wd,
                                              const float* __restrict__ ws,
                                              unsigned short* __restrict__ Wb) {
    const int o = blockIdx.x, t = threadIdx.x;
    const int4* p = reinterpret_cast<const int4*>(&wd[(size_t)o * (K_DIM / 2) + t * 8]);
    int4 w0 = p[0], w1 = p[1];
    const float s = ws[o * 32 + (t >> 3)];   // k0 = t*16, group = t*16/128
    int wv[8] = {w0.x, w0.y, w0.z, w0.w, w1.x, w1.y, w1.z, w1.w};
    u16x8 h0, h1;
    #pragma unroll
    for (int m = 0; m < 8; ++m) {
        unsigned short lo = bf16_rne((float)((wv[m] & 0xF) - 8) * s);
        unsigned short hi = bf16_rne((float)(((wv[m] >> 4) & 0xF) - 8) * s);
        if (m < 4) { h0[2 * m] = lo; h0[2 * m + 1] = hi; }
        else       { h1[2 * (m - 4)] = lo; h1[2 * (m - 4) + 1] = hi; }
    }
    size_t oo = (size_t)o * K_DIM + t * 16;
    *reinterpret_cast<u16x8*>(&Wb[oo]) = h0;
    *reinterpret_cast<u16x8*>(&Wb[oo + 8]) = h1;
}

// ---------- 256x256 GEMM, BK=32, 4-slot ring + register fragment pipeline ----------
// A [m][k] bf16, B [n][k] bf16. 8 waves 2x4; wave owns 128x64 (8x4 frags).
// MODE 0: C -> bf16 (Cb).  MODE 1: C -> f32 + bias (Cf).
template <int MODE>
__global__ __launch_bounds__(512) void gemm_cv(const unsigned short* __restrict__ A,
                                               const unsigned short* __restrict__ B,
                                               const float* __restrict__ bias,
                                               unsigned short* __restrict__ Cb,
                                               float* __restrict__ Cf) {
    extern __shared__ unsigned short sm[];   // 4 slots x (A 8192 | B 8192) ushorts
    const int t = threadIdx.x;
    const int lane = t & 63;
    const int wid = __builtin_amdgcn_readfirstlane(t >> 6);
    const int wr = wid >> 2, wc = wid & 3;   // 2 x 4 wave grid

    // XCD-aware bijective swizzle: 256 blocks, 8 XCDs, 256%8==0
    const int fid = blockIdx.x;
    const int sw = (fid & 7) * 32 + (fid >> 3);
    const int bm = (sw >> 4) * 256;
    const int bn = (sw & 15) * 256;

    // staging: per matrix tile 1024 chunks (256 rows x 4 chunks of 16B),
    // 2 chunks/thread. LDS dest linear; SOURCE pre-swizzled:
    // logical chunk = physical ^ ((row>>1)&3)  (r4/r6/r10 proven-zero layout).
    size_t ga[2], gb[2];
    int lb[2];
    #pragma unroll
    for (int j = 0; j < 2; ++j) {
        int ch = wid * 128 + j * 64 + lane;
        int row = ch >> 2, qp = ch & 3;
        int qs = qp ^ ((row >> 1) & 3);
        ga[j] = (size_t)(bm + row) * K_DIM + qs * 8;
        gb[j] = (size_t)(bn + row) * K_DIM + qs * 8;
        lb[j] = (wid * 128 + j * 64) * 8;    // wave-uniform, HW adds lane*16B
    }

    // fragment reads: row r, chunk lk -> physical lk ^ ((r>>1)&3)
    const int lr = lane & 15, lk = lane >> 4;
    int aoff[8], boff[4], colj[4];
    #pragma unroll
    for (int i = 0; i < 8; ++i) {
        int ra = wr * 128 + i * 16 + lr;
        aoff[i] = ra * 32 + (lk ^ ((ra >> 1) & 3)) * 8;
    }
    #pragma unroll
    for (int j = 0; j < 4; ++j) {
        int rb = wc * 64 + j * 16 + lr;
        boff[j] = rb * 32 + (lk ^ ((rb >> 1) & 3)) * 8;
        colj[j] = bn + wc * 64 + j * 16 + lr;
    }

    f32x4 acc[8][4];
    #pragma unroll
    for (int i = 0; i < 8; ++i)
        #pragma unroll
        for (int j = 0; j < 4; ++j) acc[i][j] = {0.f, 0.f, 0.f, 0.f};

#define LD8(p) (*reinterpret_cast<const s8v*>(p))

#define STAGE(tt)                                                                                      \
    {                                                                                                  \
        const int _sl = ((tt) & 3) * 16384;                                                            \
        _Pragma("unroll")                                                                              \
        for (int j = 0; j < 2; ++j) {                                                                  \
            __builtin_amdgcn_global_load_lds(AS1(A + ga[j] + (tt) * 32), AS3(&sm[_sl + lb[j]]), 16, 0, 0); \
            __builtin_amdgcn_global_load_lds(AS1(B + gb[j] + (tt) * 32), AS3(&sm[_sl + 8192 + lb[j]]), 16, 0, 0); \
        }                                                                                              \
    }

// plain compute (tail only): reads all 12 frags from LDS
#define COMPUTE(tt)                                                                                    \
    {                                                                                                  \
        const unsigned short* _pa = &sm[((tt) & 3) * 16384];                                           \
        const unsigned short* _pb = _pa + 8192;                                                        \
        s8v av[8], bv[4];                                                                              \
        _Pragma("unroll")                                                                              \
        for (int j = 0; j < 4; ++j) bv[j] = LD8(&_pb[boff[j]]);                                        \
        _Pragma("unroll")                                                                              \
        for (int i = 0; i < 8; ++i) av[i] = LD8(&_pa[aoff[i]]);                                        \
        _Pragma("unroll")                                                                              \
        for (int i = 0; i < 8; ++i)                                                                    \
            _Pragma("unroll")                                                                          \
            for (int j = 0; j < 4; ++j)                                                                \
                acc[i][j] = __builtin_amdgcn_mfma_f32_16x16x32_bf16(av[i], bv[j], acc[i][j], 0, 0, 0); \
    }

#define SYNCN(N)                                                                                       \
    asm volatile("s_waitcnt vmcnt(" #N ")" ::: "memory");                                              \
    __builtin_amdgcn_s_barrier();                                                                      \
    __builtin_amdgcn_sched_barrier(0);

// pipelined sub-iter for tile U: MFMA with bvU (already in regs), av JIT
// ping-pong; fill bvF with tile U+1's B-frags (visible: retired end of iter
// U-1 under vmcnt(4)); stage U+3; retire to 4 outstanding.
#define SUBITER(U, bvU, bvF)                                                                           \
    {                                                                                                  \
        const unsigned short* _pa = &sm[((U) & 3) * 16384];                                            \
        const unsigned short* _pn = &sm[(((U) + 1) & 3) * 16384] + 8192;                               \
        s8v av_e, av_o;                                                                                \
        av_e = LD8(&_pa[aoff[0]]);                                                                     \
        _Pragma("unroll")                                                                              \
        for (int i = 0; i < 8; ++i) {                                                                  \
            if (i < 7) {                                                                               \
                if (i & 1) av_e = LD8(&_pa[aoff[i + 1]]);                                              \
                else       av_o = LD8(&_pa[aoff[i + 1]]);                                              \
            }                                                                                          \
            if (i >= 2 && i < 6) bvF[i - 2] = LD8(&_pn[boff[i - 2]]);                                  \
            s8v _a = (i & 1) ? av_o : av_e;                                                            \
            _Pragma("unroll")                                                                          \
            for (int j = 0; j < 4; ++j)                                                                \
                acc[i][j] = __builtin_amdgcn_mfma_f32_16x16x32_bf16(_a, bvU[j], acc[i][j], 0, 0, 0);   \
        }                                                                                              \
        STAGE((U) + 3);                                                                                \
        SYNCN(4);                                                                                      \
    }

    // prologue: stage 0,1,2; retire tiles 0,1 (4 outstanding = tile 2);
    // then preload bv(tile 0) into regs.
    STAGE(0);
    STAGE(1);
    STAGE(2);
    SYNCN(4);
    s8v bvA[4], bvB[4];
    {
        const unsigned short* p0 = &sm[8192];   // slot 0, B region
        #pragma unroll
        for (int j = 0; j < 4; ++j) bvA[j] = LD8(&p0[boff[j]]);
    }
    // steady state: sub-iters u=0..123 (stages 3..126). Entering sub-iter u:
    // 4 outstanding (tile u+2), tiles <= u+1 visible.
    for (int u = 0; u + 4 < NT; u += 2) {
        SUBITER(u,     bvA, bvB);
        SUBITER(u + 1, bvB, bvA);
    }
    // tail: tiles 124..127. Stage 127 (slots 0..3 all distinct, no overwrite),
    // drain, compute plain.
    STAGE(NT - 1);
    SYNCN(0);
    COMPUTE(NT - 4);
    COMPUTE(NT - 3);
    COMPUTE(NT - 2);
    COMPUTE(NT - 1);
#undef SUBITER
#undef STAGE
#undef COMPUTE
#undef SYNCN
#undef LD8

    // epilogue — C/D frag layout: col = lane&15, row = (lane>>4)*4 + reg  [m89]
    if (MODE == 0) {
        #pragma unroll
        for (int i = 0; i < 8; ++i)
            #pragma unroll
            for (int j = 0; j < 4; ++j)
                #pragma unroll
                for (int r = 0; r < 4; ++r) {
                    int row = bm + wr * 128 + i * 16 + lk * 4 + r;
                    Cb[(size_t)row * K_DIM + colj[j]] = bf16_rne(acc[i][j][r]);
                }
    } else {
        float bj[4];
        #pragma unroll
        for (int j = 0; j < 4; ++j) bj[j] = bias[colj[j]];
        #pragma unroll
        for (int i = 0; i < 8; ++i)
            #pragma unroll
            for (int j = 0; j < 4; ++j)
                #pragma unroll
                for (int r = 0; r < 4; ++r) {
                    int row = bm + wr * 128 + i * 16 + lk * 4 + r;
                    Cf[(size_t)row * M_DIM + colj[j]] = acc[i][j][r] + bj[j];
                }
    }
}

extern "C" void kernel_launch(void* const* d_in, const int* in_sizes, int n_in,
                              void* d_out, int out_size, void* d_ws, size_t ws_size,
                              hipStream_t stream) {
    const float* x      = (const float*)d_in[0];
    const float* had    = (const float*)d_in[1];
    const float* wscale = (const float*)d_in[2];
    const float* bias   = (const float*)d_in[3];
    const int*   wdata  = (const int*)d_in[4];
    float* out = (float*)d_out;

    const size_t SEG = (size_t)N_TOK * K_DIM * 2;   // 32 MiB
    char* w = (char*)d_ws;
    unsigned short* xh  = (unsigned short*)(w);            // [0,32Mi)
    unsigned short* Hh  = (unsigned short*)(w + SEG);      // [32,64Mi)
    unsigned short* xrh = (unsigned short*)(w + 2 * SEG);  // [64,96Mi)
    unsigned short* Wb  = (unsigned short*)(w + 3 * SEG);  // [96,128Mi)

    // allow 128 KiB dynamic LDS (host-side idempotent config; guarded so the
    // graph-captured replay path never re-executes it — proven r10-r13)
    static bool attr_done = false;
    if (!attr_done) {
        hipFuncSetAttribute((const void*)gemm_cv<0>,
                            hipFuncAttributeMaxDynamicSharedMemorySize, 131072);
        hipFuncSetAttribute((const void*)gemm_cv<1>,
                            hipFuncAttributeMaxDynamicSharedMemorySize, 131072);
        attr_done = true;
    }

    prep_cast<<<(N_TOK * K_DIM) / (256 * 8), 256, 0, stream>>>(x, xh);
    prep_hT<<<dim3(64, 64), 256, 0, stream>>>(had, Hh);
    prep_w<<<M_DIM, 256, 0, stream>>>(wdata, wscale, Wb);
    gemm_cv<0><<<256, 512, 131072, stream>>>(xh, Hh, nullptr, xrh, nullptr);
    gemm_cv<1><<<256, 512, 131072, stream>>>(xrh, Wb, bias, nullptr, out);
}

// Round 15
// 269.420 us; speedup vs baseline: 1.1380x; 1.0453x over previous
//
#include <hip/hip_runtime.h>

// QuantizedLinear on MI355X — round 15: consolidation (fused preps + piped tail).
//   out = (x @ H) @ dequant(W)^T + bias
// GEMM1 xh·Hh, GEMM2 xrh·Wb (Wb = bf16((nibble-8)*scale)) — validated r8-r14.
// Core = r14 (best measured): 256x256 tile, BK=32, 8 waves (2Mx4N), 4-slot
// LDS ring (128 KiB), counted vmcnt(4), register bv-double-buffer + av JIT
// ping-pong, 64 B-row XOR swizzle both-sides (0 conflicts), XCD swizzle.
// NEW: (1) three prep kernels fused into ONE launch (block-range dispatch) —
// saves ~2 inter-dispatch gaps; (2) GEMM tail pipelined: SUBITER through tile
// NT-4 (stages NT-1), then stepped drain 4->0 keeping bv prefetch — removes
// the full-drain + 4 serial un-piped computes of r14's tail.
// Session ledger: 2-barrier-class plateau at ~1175 TF/GEMM confirmed by 3
// nulls (r11 phase-split, r12 depth, r14 reg-pipe) + 1 negative (r13).
// Requires 128 MiB d_ws (192 proven).

#define N_TOK 4096
#define K_DIM 4096
#define M_DIM 4096
#define NT    128          // K tiles (4096/32)

typedef __attribute__((ext_vector_type(8))) short s8v;       // 8 bf16 (4 VGPR)
typedef __attribute__((ext_vector_type(4))) float f32x4;
typedef __attribute__((ext_vector_type(4))) unsigned short u16x4;
typedef __attribute__((ext_vector_type(8))) unsigned short u16x8;

#define AS1(p) ((const __attribute__((address_space(1))) void*)(p))
#define AS3(p) ((__attribute__((address_space(3))) void*)(p))

__device__ __forceinline__ unsigned short bf16_rne(float f) {
    unsigned int u = __float_as_uint(f);
    unsigned int r = (u + 0x7FFFu + ((u >> 16) & 1u)) >> 16;
    return (unsigned short)r;
}

// ---------- fused prep: [0,8192) cast x | [8192,12288) transpose H | [12288,16384) dequant W ----------
__global__ __launch_bounds__(256) void prep_fused(const float* __restrict__ x,
                                                  const float* __restrict__ H,
                                                  const int* __restrict__ wd,
                                                  const float* __restrict__ ws,
                                                  unsigned short* __restrict__ xh,
                                                  unsigned short* __restrict__ Th,
                                                  unsigned short* __restrict__ Wb) {
    __shared__ float tile[64][65];
    const int bid = blockIdx.x;
    const int t = threadIdx.x;
    if (bid < 8192) {
        // cast fp32 -> bf16 (RNE), x8 vectorized
        size_t i = ((size_t)bid * 256 + t) * 8;
        float4 v0 = *reinterpret_cast<const float4*>(&x[i]);
        float4 v1 = *reinterpret_cast<const float4*>(&x[i + 4]);
        u16x8 h;
        h[0] = bf16_rne(v0.x); h[1] = bf16_rne(v0.y);
        h[2] = bf16_rne(v0.z); h[3] = bf16_rne(v0.w);
        h[4] = bf16_rne(v1.x); h[5] = bf16_rne(v1.y);
        h[6] = bf16_rne(v1.z); h[7] = bf16_rne(v1.w);
        *reinterpret_cast<u16x8*>(&xh[i]) = h;
    } else if (bid < 12288) {
        // transpose H -> Th (bf16) stored [n][k]
        const int b = bid - 8192;
        const int tx = t & 15, ty = t >> 4;
        const int c0 = (b & 63) * 64, r0 = (b >> 6) * 64;
        #pragma unroll
        for (int rr = 0; rr < 4; ++rr) {
            int r = ty + rr * 16;
            float4 v = *reinterpret_cast<const float4*>(&H[(size_t)(r0 + r) * K_DIM + c0 + tx * 4]);
            tile[r][tx * 4 + 0] = v.x;
            tile[r][tx * 4 + 1] = v.y;
            tile[r][tx * 4 + 2] = v.z;
            tile[r][tx * 4 + 3] = v.w;
        }
        __syncthreads();
        #pragma unroll
        for (int rr = 0; rr < 4; ++rr) {
            int c = ty + rr * 16;
            u16x4 h;
            #pragma unroll
            for (int e = 0; e < 4; ++e) h[e] = bf16_rne(tile[tx * 4 + e][c]);
            size_t o = (size_t)(c0 + c) * K_DIM + r0 + tx * 4;
            *reinterpret_cast<u16x4*>(&Th[o]) = h;
        }
    } else {
        // dequant int4 -> bf16 (nibble-8)*scale
        const int o = bid - 12288;
        const int4* p = reinterpret_cast<const int4*>(&wd[(size_t)o * (K_DIM / 2) + t * 8]);
        int4 w0 = p[0], w1 = p[1];
        const float s = ws[o * 32 + (t >> 3)];   // k0 = t*16, group = t*16/128
        int wv[8] = {w0.x, w0.y, w0.z, w0.w, w1.x, w1.y, w1.z, w1.w};
        u16x8 h0, h1;
        #pragma unroll
        for (int m = 0; m < 8; ++m) {
            unsigned short lo = bf16_rne((float)((wv[m] & 0xF) - 8) * s);
            unsigned short hi = bf16_rne((float)(((wv[m] >> 4) & 0xF) - 8) * s);
            if (m < 4) { h0[2 * m] = lo; h0[2 * m + 1] = hi; }
            else       { h1[2 * (m - 4)] = lo; h1[2 * (m - 4) + 1] = hi; }
        }
        size_t oo = (size_t)o * K_DIM + t * 16;
        *reinterpret_cast<u16x8*>(&Wb[oo]) = h0;
        *reinterpret_cast<u16x8*>(&Wb[oo + 8]) = h1;
    }
}

// ---------- 256x256 GEMM, BK=32, 4-slot ring + register fragment pipeline ----------
// A [m][k] bf16, B [n][k] bf16. 8 waves 2x4; wave owns 128x64 (8x4 frags).
// MODE 0: C -> bf16 (Cb).  MODE 1: C -> f32 + bias (Cf).
template <int MODE>
__global__ __launch_bounds__(512) void gemm_cv(const unsigned short* __restrict__ A,
                                               const unsigned short* __restrict__ B,
                                               const float* __restrict__ bias,
                                               unsigned short* __restrict__ Cb,
                                               float* __restrict__ Cf) {
    extern __shared__ unsigned short sm[];   // 4 slots x (A 8192 | B 8192) ushorts
    const int t = threadIdx.x;
    const int lane = t & 63;
    const int wid = __builtin_amdgcn_readfirstlane(t >> 6);
    const int wr = wid >> 2, wc = wid & 3;   // 2 x 4 wave grid

    // XCD-aware bijective swizzle: 256 blocks, 8 XCDs, 256%8==0
    const int fid = blockIdx.x;
    const int sw = (fid & 7) * 32 + (fid >> 3);
    const int bm = (sw >> 4) * 256;
    const int bn = (sw & 15) * 256;

    // staging: per matrix tile 1024 chunks (256 rows x 4 chunks of 16B),
    // 2 chunks/thread. LDS dest linear; SOURCE pre-swizzled:
    // logical chunk = physical ^ ((row>>1)&3)  (r4/r6/r10 proven-zero layout).
    size_t ga[2], gb[2];
    int lb[2];
    #pragma unroll
    for (int j = 0; j < 2; ++j) {
        int ch = wid * 128 + j * 64 + lane;
        int row = ch >> 2, qp = ch & 3;
        int qs = qp ^ ((row >> 1) & 3);
        ga[j] = (size_t)(bm + row) * K_DIM + qs * 8;
        gb[j] = (size_t)(bn + row) * K_DIM + qs * 8;
        lb[j] = (wid * 128 + j * 64) * 8;    // wave-uniform, HW adds lane*16B
    }

    // fragment reads: row r, chunk lk -> physical lk ^ ((r>>1)&3)
    const int lr = lane & 15, lk = lane >> 4;
    int aoff[8], boff[4], colj[4];
    #pragma unroll
    for (int i = 0; i < 8; ++i) {
        int ra = wr * 128 + i * 16 + lr;
        aoff[i] = ra * 32 + (lk ^ ((ra >> 1) & 3)) * 8;
    }
    #pragma unroll
    for (int j = 0; j < 4; ++j) {
        int rb = wc * 64 + j * 16 + lr;
        boff[j] = rb * 32 + (lk ^ ((rb >> 1) & 3)) * 8;
        colj[j] = bn + wc * 64 + j * 16 + lr;
    }

    f32x4 acc[8][4];
    #pragma unroll
    for (int i = 0; i < 8; ++i)
        #pragma unroll
        for (int j = 0; j < 4; ++j) acc[i][j] = {0.f, 0.f, 0.f, 0.f};

#define LD8(p) (*reinterpret_cast<const s8v*>(p))

#define STAGE(tt)                                                                                      \
    {                                                                                                  \
        const int _sl = ((tt) & 3) * 16384;                                                            \
        _Pragma("unroll")                                                                              \
        for (int j = 0; j < 2; ++j) {                                                                  \
            __builtin_amdgcn_global_load_lds(AS1(A + ga[j] + (tt) * 32), AS3(&sm[_sl + lb[j]]), 16, 0, 0); \
            __builtin_amdgcn_global_load_lds(AS1(B + gb[j] + (tt) * 32), AS3(&sm[_sl + 8192 + lb[j]]), 16, 0, 0); \
        }                                                                                              \
    }

#define SYNCN(N)                                                                                       \
    asm volatile("s_waitcnt vmcnt(" #N ")" ::: "memory");                                              \
    __builtin_amdgcn_s_barrier();                                                                      \
    __builtin_amdgcn_sched_barrier(0);

// pipelined sub-iter for tile U: MFMA with bvU (in regs), av JIT ping-pong;
// optionally fill bvF with tile U+1's B-frags; optionally stage U+3.
#define SUBITER_CORE(U, bvU, bvF, DOSTAGE, DOFILL)                                                     \
    {                                                                                                  \
        const unsigned short* _pa = &sm[((U) & 3) * 16384];                                            \
        const unsigned short* _pn = &sm[(((U) + 1) & 3) * 16384] + 8192;                               \
        s8v av_e, av_o;                                                                                \
        av_e = LD8(&_pa[aoff[0]]);                                                                     \
        _Pragma("unroll")                                                                              \
        for (int i = 0; i < 8; ++i) {                                                                  \
            if (i < 7) {                                                                               \
                if (i & 1) av_e = LD8(&_pa[aoff[i + 1]]);                                              \
                else       av_o = LD8(&_pa[aoff[i + 1]]);                                              \
            }                                                                                          \
            if ((DOFILL) && i >= 2 && i < 6) bvF[i - 2] = LD8(&_pn[boff[i - 2]]);                      \
            s8v _a = (i & 1) ? av_o : av_e;                                                            \
            _Pragma("unroll")                                                                          \
            for (int j = 0; j < 4; ++j)                                                                \
                acc[i][j] = __builtin_amdgcn_mfma_f32_16x16x32_bf16(_a, bvU[j], acc[i][j], 0, 0, 0);   \
        }                                                                                              \
        if (DOSTAGE) STAGE((U) + 3);                                                                   \
    }

    // prologue: stage 0,1,2; retire tiles 0,1 (4 outstanding = tile 2);
    // preload bv(tile 0) into regs.
    STAGE(0);
    STAGE(1);
    STAGE(2);
    SYNCN(4);
    s8v bvA[4], bvB[4];
    {
        const unsigned short* p0 = &sm[8192];   // slot 0, B region
        #pragma unroll
        for (int j = 0; j < 4; ++j) bvA[j] = LD8(&p0[boff[j]]);
    }
    // steady state: pairs through tile NT-5=123 (stages through 126).
    // Invariant entering tile u: 4 outstanding (tile u+2), tiles <= u+1 visible.
    for (int u = 0; u + 4 < NT; u += 2) {
        SUBITER_CORE(u, bvA, bvB, 1, 1);
        SYNCN(4);
        SUBITER_CORE(u + 1, bvB, bvA, 1, 1);
        SYNCN(4);
    }
    // pipelined tail: 124 stages 127; then stepped drain keeping bv prefetch.
    SUBITER_CORE(NT - 4, bvA, bvB, 1, 1);   // tile 124, stages 127
    SYNCN(4);                                // retire 126; outstanding = 127's
    SUBITER_CORE(NT - 3, bvB, bvA, 0, 1);   // tile 125, bvA <- bv(126)
    SYNCN(0);                                // retire 127; all visible
    SUBITER_CORE(NT - 2, bvA, bvB, 0, 1);   // tile 126, bvB <- bv(127)
    SUBITER_CORE(NT - 1, bvB, bvA, 0, 0);   // tile 127
#undef SUBITER_CORE
#undef STAGE
#undef SYNCN
#undef LD8

    // epilogue — C/D frag layout: col = lane&15, row = (lane>>4)*4 + reg  [m89]
    if (MODE == 0) {
        #pragma unroll
        for (int i = 0; i < 8; ++i)
            #pragma unroll
            for (int j = 0; j < 4; ++j)
                #pragma unroll
                for (int r = 0; r < 4; ++r) {
                    int row = bm + wr * 128 + i * 16 + lk * 4 + r;
                    Cb[(size_t)row * K_DIM + colj[j]] = bf16_rne(acc[i][j][r]);
                }
    } else {
        float bj[4];
        #pragma unroll
        for (int j = 0; j < 4; ++j) bj[j] = bias[colj[j]];
        #pragma unroll
        for (int i = 0; i < 8; ++i)
            #pragma unroll
            for (int j = 0; j < 4; ++j)
                #pragma unroll
                for (int r = 0; r < 4; ++r) {
                    int row = bm + wr * 128 + i * 16 + lk * 4 + r;
                    Cf[(size_t)row * M_DIM + colj[j]] = acc[i][j][r] + bj[j];
                }
    }
}

extern "C" void kernel_launch(void* const* d_in, const int* in_sizes, int n_in,
                              void* d_out, int out_size, void* d_ws, size_t ws_size,
                              hipStream_t stream) {
    const float* x      = (const float*)d_in[0];
    const float* had    = (const float*)d_in[1];
    const float* wscale = (const float*)d_in[2];
    const float* bias   = (const float*)d_in[3];
    const int*   wdata  = (const int*)d_in[4];
    float* out = (float*)d_out;

    const size_t SEG = (size_t)N_TOK * K_DIM * 2;   // 32 MiB
    char* w = (char*)d_ws;
    unsigned short* xh  = (unsigned short*)(w);            // [0,32Mi)
    unsigned short* Hh  = (unsigned short*)(w + SEG);      // [32,64Mi)
    unsigned short* xrh = (unsigned short*)(w + 2 * SEG);  // [64,96Mi)
    unsigned short* Wb  = (unsigned short*)(w + 3 * SEG);  // [96,128Mi)

    // allow 128 KiB dynamic LDS (host-side idempotent config; guarded so the
    // graph-captured replay path never re-executes it — proven r10-r14)
    static bool attr_done = false;
    if (!attr_done) {
        hipFuncSetAttribute((const void*)gemm_cv<0>,
                            hipFuncAttributeMaxDynamicSharedMemorySize, 131072);
        hipFuncSetAttribute((const void*)gemm_cv<1>,
                            hipFuncAttributeMaxDynamicSharedMemorySize, 131072);
        attr_done = true;
    }

    prep_fused<<<16384, 256, 0, stream>>>(x, had, wdata, wscale, xh, Hh, Wb);
    gemm_cv<0><<<256, 512, 131072, stream>>>(xh, Hh, nullptr, xrh, nullptr);
    gemm_cv<1><<<256, 512, 131072, stream>>>(xrh, Wb, bias, nullptr, out);
}